// Round 1
// baseline (26.734 us; speedup 1.0000x reference)
//
#include <hip/hip_runtime.h>

#define HH 128
#define WW 128
#define CC 3
#define TILE 8
#define HALO 12      // TILE + 2*2 neighbor halo
#define IMGT 18      // TILE + 2*2 + 2*3 patch halo
#define PATCH 49
#define NW 4         // waves per block
#define NPB 6        // neighbors handled per thread (24 / NW)

__global__ __launch_bounds__(256, 2)
void err_neurons_kernel(const float* __restrict__ img, float* __restrict__ out) {
    __shared__ float s_img[IMGT * IMGT];
    __shared__ float s_g[HALO * HALO * PATCH];
    __shared__ float s_nsq[HALO * HALO];
    __shared__ float s_red[2 * 256];

    const int tid  = threadIdx.x;
    const int lane = tid & 63;
    const int w    = tid >> 6;
    const int bx = blockIdx.x, by = blockIdx.y, b = blockIdx.z;
    const int x0 = bx * TILE, y0 = by * TILE;
    const int py = lane >> 3, px = lane & 7;
    const int gy = y0 + py, gx = x0 + px;

    // This thread's 6 neighbor offsets (5x5 window minus center, row-major)
    int  npn[NPB];
    bool nvalid[NPB];
#pragma unroll
    for (int j = 0; j < NPB; ++j) {
        int s = w * NPB + j;
        int u = s + (s >= 12 ? 1 : 0);   // skip center index 12
        int dy = u / 5 - 2, dx = u % 5 - 2;
        int ny = gy + dy, nx = gx + dx;
        nvalid[j] = (ny >= 0 && ny < HH && nx >= 0 && nx < WW);
        npn[j] = (py + 2 + dy) * HALO + (px + 2 + dx);
    }
    const int p0 = (py + 2) * HALO + (px + 2);

    float dots[NPB];
#pragma unroll
    for (int j = 0; j < NPB; ++j) dots[j] = 0.f;

    const float* imgb = img + (size_t)b * CC * HH * WW;

    for (int c = 0; c < CC; ++c) {
        __syncthreads();   // previous channel's g reads complete
        // Stage 18x18 image tile (origin y0-5, x0-5), zero padded
        for (int i = tid; i < IMGT * IMGT; i += 256) {
            int iy = i / IMGT, ix = i % IMGT;
            int yy = y0 - 5 + iy, xx = x0 - 5 + ix;
            float v = 0.f;
            if (yy >= 0 && yy < HH && xx >= 0 && xx < WW)
                v = imgb[(size_t)c * HH * WW + yy * WW + xx];
            s_img[i] = v;
        }
        __syncthreads();
        // LayerNorm the 12x12 halo pixels' 7x7 patches
        if (tid < HALO * HALO) {
            int hy = tid / HALO, hx = tid % HALO;
            int yy = y0 - 2 + hy, xx = x0 - 2 + hx;
            if (yy >= 0 && yy < HH && xx >= 0 && xx < WW) {
                float sum = 0.f, sum2 = 0.f;
#pragma unroll
                for (int di = 0; di < 7; ++di)
#pragma unroll
                    for (int dj = 0; dj < 7; ++dj) {
                        float v = s_img[(hy + di) * IMGT + hx + dj];
                        sum += v; sum2 += v * v;
                    }
                float mu   = sum * (1.f / 49.f);
                float var  = sum2 * (1.f / 49.f) - mu * mu;
                float rinv = rsqrtf(var + 1e-5f);
                float nsq  = 0.f;
                float* gp  = &s_g[tid * PATCH];
#pragma unroll
                for (int di = 0; di < 7; ++di)
#pragma unroll
                    for (int dj = 0; dj < 7; ++dj) {
                        float v  = s_img[(hy + di) * IMGT + hx + dj];
                        float gg = (v - mu) * rinv + 2.f;
                        gp[di * 7 + dj] = gg;
                        nsq += gg * gg;
                    }
                s_nsq[tid] = (c == 0 ? 0.f : s_nsq[tid]) + nsq;
            }
        }
        __syncthreads();
        // Accumulate dot products: own feature row cached in registers
        float own[PATCH];
        const float* g0 = &s_g[p0 * PATCH];
#pragma unroll
        for (int k = 0; k < PATCH; ++k) own[k] = g0[k];
#pragma unroll
        for (int j = 0; j < NPB; ++j) {
            if (!nvalid[j]) continue;
            const float* gn = &s_g[npn[j] * PATCH];
            float acc = dots[j];
#pragma unroll
            for (int k = 0; k < PATCH; ++k) acc += own[k] * gn[k];
            dots[j] = acc;
        }
    }

    // Finalize: cosine distance, masked mean over this thread's neighbors
    float nt = sqrtf(s_nsq[p0]);
    float lsum = 0.f, lcnt = 0.f;
#pragma unroll
    for (int j = 0; j < NPB; ++j) {
        if (!nvalid[j]) continue;
        float nu    = sqrtf(s_nsq[npn[j]]);
        float denom = fmaxf(nt * nu, 1e-8f);
        float cosv  = dots[j] / denom;
        lsum += (1.f - cosv) * 0.5f;
        lcnt += 1.f;
    }
    s_red[w * 64 + lane]       = lsum;
    s_red[256 + w * 64 + lane] = lcnt;
    __syncthreads();
    if (tid < 64) {
        float ss = 0.f, sc = 0.f;
#pragma unroll
        for (int w2 = 0; w2 < NW; ++w2) {
            ss += s_red[w2 * 64 + tid];
            sc += s_red[256 + w2 * 64 + tid];
        }
        out[(size_t)b * HH * WW + gy * WW + gx] = ss / sc;
    }
}

extern "C" void kernel_launch(void* const* d_in, const int* in_sizes, int n_in,
                              void* d_out, int out_size, void* d_ws, size_t ws_size,
                              hipStream_t stream) {
    const float* img = (const float*)d_in[0];
    float* out = (float*)d_out;
    dim3 grid(WW / TILE, HH / TILE, 2);
    dim3 block(256);
    hipLaunchKernelGGL(err_neurons_kernel, grid, block, 0, stream, img, out);
}

// Round 2
// 15.429 us; speedup vs baseline: 1.7327x; 1.7327x over previous
//
#include <hip/hip_runtime.h>

#define HH 128
#define WW 128
#define CC 3
#define TX 16                 // tile width
#define TY 8                  // tile height
#define NPIX (TX*TY)          // 128 pixels per block
#define SW (TX+4)             // 20 stats cols (±2 neighbor halo)
#define SH (TY+4)             // 12 stats rows
#define NST (SW*SH)           // 240 stats positions
#define IW (TX+10)            // 26 img tile cols (±5 total halo)
#define IH (TY+10)            // 18 img tile rows
#define NIMG (IW*IH)          // 468
#define PSTRIDE 25            // 24 neighbors padded to odd stride (bank-safe)
#define NTHR 384              // 128 px * 3 channels

__global__ __launch_bounds__(NTHR, 1)
void err_neurons_kernel(const float* __restrict__ img, float* __restrict__ out) {
    __shared__ float s_img[CC][NIMG];
    __shared__ float s_mu[CC][NST];
    __shared__ float s_r[CC][NST];
    __shared__ float s_nsqc[CC][NST];
    __shared__ float s_nrm[NST];
    __shared__ float s_part[CC][NPIX * PSTRIDE];

    const int tid = threadIdx.x;
    const int bx = blockIdx.x, by = blockIdx.y, b = blockIdx.z;
    const int x0 = bx * TX, y0 = by * TY;
    const float* imgb = img + (size_t)b * CC * HH * WW;

    // ---- Phase 1: stage zero-padded 26x18 image tiles, all 3 channels ----
    for (int i = tid; i < CC * NIMG; i += NTHR) {
        int c = i / NIMG, r = i % NIMG;
        int iy = r / IW, ix = r % IW;
        int yy = y0 - 5 + iy, xx = x0 - 5 + ix;
        float v = 0.f;
        if (yy >= 0 && yy < HH && xx >= 0 && xx < WW)
            v = imgb[(size_t)c * HH * WW + yy * WW + xx];
        s_img[c][r] = v;
    }
    __syncthreads();

    // ---- Phase 2: per-(channel, stats-pos) 7x7 mean/var -> mu, r, normsq ----
    for (int s = tid; s < CC * NST; s += NTHR) {
        int c = s / NST, pos = s % NST;
        int sy = pos / SW, sx = pos % SW;
        const float* base = &s_img[c][sy * IW + sx];
        float sum = 0.f, sum2 = 0.f;
#pragma unroll
        for (int i = 0; i < 7; ++i)
#pragma unroll
            for (int j = 0; j < 7; ++j) {
                float v = base[i * IW + j];
                sum += v; sum2 = fmaf(v, v, sum2);
            }
        float mu  = sum * (1.f / 49.f);
        float var = fmaf(-mu, mu, sum2 * (1.f / 49.f));
        var = fmaxf(var, 0.f);
        float r = rsqrtf(var + 1e-5f);
        s_mu[c][pos] = mu;
        s_r[c][pos]  = r;
        s_nsqc[c][pos] = fmaf(49.f * var, r * r, 196.f);
    }
    __syncthreads();
    if (tid < NST)
        s_nrm[tid] = sqrtf(s_nsqc[0][tid] + s_nsqc[1][tid] + s_nsqc[2][tid]);
    __syncthreads();

    // ---- Phase 3: per-(pixel, channel) cross-correlations, closed form ----
    {
        const int p = tid % NPIX, c = tid / NPIX;
        const int x = p % TX, y = p / TX;
        // 11x11 raw-image window around this pixel, in registers
        float R[11][11];
#pragma unroll
        for (int a = 0; a < 11; ++a)
#pragma unroll
            for (int bb = 0; bb < 11; ++bb)
                R[a][bb] = s_img[c][(y + a) * IW + (x + bb)];
        const int cpos = (y + 2) * SW + (x + 2);
        const float mut = s_mu[c][cpos];
        const float rt  = s_r[c][cpos];
#pragma unroll
        for (int u = 0; u < 25; ++u) {
            if (u == 12) continue;
            const int dy = u / 5 - 2, dx = u % 5 - 2;
            const int j = u - (u > 12 ? 1 : 0);
            float cross = 0.f;
#pragma unroll
            for (int oy = 0; oy < 7; ++oy)
#pragma unroll
                for (int ox = 0; ox < 7; ++ox)
                    cross = fmaf(R[oy + 2][ox + 2], R[oy + 2 + dy][ox + 2 + dx], cross);
            const int upos = (y + 2 + dy) * SW + (x + 2 + dx);
            float part = (cross - 49.f * mut * s_mu[c][upos]) * rt * s_r[c][upos];
            s_part[c][p * PSTRIDE + j] = part;
        }
    }
    __syncthreads();

    // ---- Phase 4: combine channels, cosine distance, masked mean ----
    if (tid < NPIX) {
        const int p = tid;
        const int x = p % TX, y = p / TX;
        const int gx = x0 + x, gy = y0 + y;
        const float nt = s_nrm[(y + 2) * SW + (x + 2)];
        float acc = 0.f, cnt = 0.f;
#pragma unroll
        for (int u = 0; u < 25; ++u) {
            if (u == 12) continue;
            const int dy = u / 5 - 2, dx = u % 5 - 2;
            const int j = u - (u > 12 ? 1 : 0);
            if (gy + dy < 0 || gy + dy >= HH || gx + dx < 0 || gx + dx >= WW) continue;
            float dot = 588.f + s_part[0][p * PSTRIDE + j]
                              + s_part[1][p * PSTRIDE + j]
                              + s_part[2][p * PSTRIDE + j];
            const float nu = s_nrm[(y + 2 + dy) * SW + (x + 2 + dx)];
            float cosv = dot / fmaxf(nt * nu, 1e-8f);
            acc += (1.f - cosv) * 0.5f;
            cnt += 1.f;
        }
        out[(size_t)b * HH * WW + gy * WW + gx] = acc / cnt;
    }
}

extern "C" void kernel_launch(void* const* d_in, const int* in_sizes, int n_in,
                              void* d_out, int out_size, void* d_ws, size_t ws_size,
                              hipStream_t stream) {
    const float* img = (const float*)d_in[0];
    float* out = (float*)d_out;
    dim3 grid(WW / TX, HH / TY, 2);
    dim3 block(NTHR);
    hipLaunchKernelGGL(err_neurons_kernel, grid, block, 0, stream, img, out);
}